// Round 9
// baseline (56.243 us; speedup 1.0000x reference)
//
#include <hip/hip_runtime.h>
#include <math.h>

// Problem constants (B=2, N=4096, T=2048, E=8192, MAX_DELAY=64)
static constexpr int NN = 4096;
static constexpr int TT = 2048;
static constexpr int EE = 8192;
static constexpr int TK = 64;
static constexpr int CAP = 32;                  // max in-degree (Poisson lam=2)
static constexpr int HALO = 80;                 // zero halo, covers delta<=5 lookback
static constexpr int XROW = HALO + TT;          // 2128 elems = 4256 B (16B multiple)
static constexpr int TABS = 104;                // tab row stride (13x8: spreads A-read banks)

typedef __attribute__((ext_vector_type(8))) short        short8v;  // 8 bf16
typedef __attribute__((ext_vector_type(4))) float        float4v;  // MFMA acc
typedef __attribute__((ext_vector_type(2))) unsigned int uint2v;

__device__ __forceinline__ unsigned cvtpk_bf16(float lo, float hi) {
    unsigned r;                      // D[15:0]=bf16(lo), D[31:16]=bf16(hi), RNE
    asm("v_cvt_pk_bf16_f32 %0, %1, %2" : "=v"(r) : "v"(lo), "v"(hi));
    return r;
}

// ---------------------------------------------------------------------------
// K1: fused prep.
//   blocks [0,1024):    x fp32 -> xb bf16, HALO-padded rows (8 rows/block;
//                       1024 x 8 = 8192 rows exactly) + zero the halo.
//   blocks [1024,2048): per-node IRF -> hirf fp32 + hb bf16
//   blocks [2048,2064): zero cnt
// ---------------------------------------------------------------------------
__global__ void prep_kernel(const float* __restrict__ params,
                            const float* __restrict__ x,
                            float* __restrict__ hirf, unsigned short* __restrict__ hb,
                            unsigned short* __restrict__ xb, int* __restrict__ cnt) {
    int blk = blockIdx.x;
    if (blk < 1024) {                           // convert 8 rows, halo-padded dst
        #pragma unroll
        for (int rr = 0; rr < 8; ++rr) {
            size_t row = (size_t)blk * 8 + rr;
            const float4* src = reinterpret_cast<const float4*>(x) + row * (TT / 4);
            unsigned short* drow = xb + row * XROW;
            if (threadIdx.x < 10)               // 80 halo elems = 10 x 16B
                reinterpret_cast<uint4*>(drow)[threadIdx.x] = make_uint4(0, 0, 0, 0);
            #pragma unroll
            for (int c = 0; c < 2; ++c) {
                int u = threadIdx.x + 256 * c;  // float4 index within row
                float4 v = src[u];
                uint2v o; o.x = cvtpk_bf16(v.x, v.y); o.y = cvtpk_bf16(v.z, v.w);
                *reinterpret_cast<uint2v*>(drow + HALO + 4 * u) = o;
            }
        }
    } else if (blk < 2048) {                    // IRF
        int t = (blk - 1024) * 256 + threadIdx.x;
        int node = t >> 6, lane = t & 63;
        float p = params[node * 2];
        float sp = fmaxf(p, 0.f) + log1pf(expf(-fabsf(p)));   // stable softplus
        float kst = sp + 0.1f;
        float inv = 1.0f / kst;
        float hv = expf(-(float)lane * inv) * inv;
        float s = hv;
        #pragma unroll
        for (int d = 1; d < 64; d <<= 1) s += __shfl_xor(s, d, 64);
        float val = hv / s;
        hirf[node * TK + lane] = val;
        hb[node * TK + lane] = (unsigned short)(cvtpk_bf16(val, val) & 0xffffu);
    } else {                                    // zero cnt
        int i = (blk - 2048) * 256 + threadIdx.x;
        if (i < NN) cnt[i] = 0;
    }
}

// ---------------------------------------------------------------------------
// K2: per-edge composed kernel (4 edges / 256-thr block) -> Kb bf16
//     + capped-list scatter (e, src) by target
// ---------------------------------------------------------------------------
__global__ void kedge_kernel(const float* __restrict__ hirf,
                             const int* __restrict__ esrc, const int* __restrict__ etgt,
                             unsigned short* __restrict__ Kb, int* __restrict__ cnt,
                             int2* __restrict__ elist2) {
    __shared__ float s_src[4][TK];
    __shared__ float s_tgt[4][TK];
    int lane = threadIdx.x & 63;
    int grp  = threadIdx.x >> 6;
    int e = blockIdx.x * 4 + grp;
    int s = esrc[e], t = etgt[e];
    s_src[grp][lane] = hirf[s * TK + lane];
    s_tgt[grp][lane] = hirf[t * TK + lane];
    __syncthreads();
    float acc = 0.f;
    for (int tau = 0; tau <= lane; ++tau)
        acc += s_tgt[grp][tau] * s_src[grp][lane - tau];
    Kb[e * TK + lane] = (unsigned short)(cvtpk_bf16(acc, acc) & 0xffffu);
    if (lane == 0) {
        int pos = atomicAdd(&cnt[t], 1);
        if (pos < CAP) elist2[t * CAP + pos] = make_int2(e, s);
    }
}

// ---------------------------------------------------------------------------
// K3: direct-global polyphase MFMA conv — NO x staging, NO barriers.
// One block per target; 256 thr = 4 INDEPENDENT waves, wave = (batch, half).
// B-fragments load straight from halo-padded xb (each lane's dwordx4 IS its
// MFMA fragment; 16B-aligned by construction).  The K-Toeplitz tab is
// wave-private LDS (same-wave DS ops are in-order -> no sync needed):
// per route: 1 Kb lane-load + 16 ds_write_b16 + 3 ds_read_b128 + 12 global
// dwordx4 + 12 MFMA.  Metadata + next-route K prefetched one route ahead.
//
//   y[16a+r] = sum_{delta,p} C[r][16*delta+p] * xrow[16*(a-delta)+p]
//   C = tab[r][80 + c] = K[r - c]  (zeros outside, written once)
// ---------------------------------------------------------------------------
__global__ __launch_bounds__(256)
void conv_dg_kernel(const unsigned short* __restrict__ xb,
                    const unsigned short* __restrict__ hb,
                    const unsigned short* __restrict__ Kb,
                    const int2* __restrict__ elist2,
                    const int* __restrict__ cnt,
                    float* __restrict__ y) {
    __shared__ unsigned short tab[4][16 * TABS];    // per-wave private

    const int tid    = threadIdx.x;
    const int wv     = tid >> 6;
    const int l      = tid & 63;
    const int lane16 = l & 15;
    const int h      = l >> 4;
    const int hlo    = h & 1, hhi = h >> 1;
    const int b      = wv >> 1;                 // batch
    const int half   = wv & 1;                  // time half
    const int tgt    = blockIdx.x;
    unsigned short* mytab = tab[wv];

    // static zero band, written once (value band below is disjoint)
    {
        int z = l & 15;
        #pragma unroll
        for (int k = 0; k < 4; ++k) {
            int r = (l >> 4) + 4 * k;           // rows 0..15
            mytab[TABS * r + z] = 0;
            mytab[TABS * r + ((z <= r) ? z + 16 : 80 + z)] = 0;
        }
    }

    float4v acc[4];
    #pragma unroll
    for (int T = 0; T < 4; ++T) acc[T] = (float4v){0.f, 0.f, 0.f, 0.f};

    // ---- metadata + K prefetch (all wave-uniform via readfirstlane) ----
    int deg = __builtin_amdgcn_readfirstlane(cnt[tgt]);
    if (deg > CAP) deg = CAP;
    const int nr = deg + 1;

    int srcCur = tgt;
    unsigned short kvCur = hb[(size_t)tgt * TK + l];
    int eN = 0, sN = 0;
    if (nr > 1) {
        int2 m = elist2[tgt * CAP];
        eN = __builtin_amdgcn_readfirstlane(m.x);
        sN = __builtin_amdgcn_readfirstlane(m.y);
    }

    for (int i = 0; i < nr; ++i) {
        const unsigned short* xr = xb + ((size_t)b * NN + srcCur) * XROW;

        // 12 B-fragment loads, straight from global (issued first, consumed last)
        short8v Bv[4][3];
        #pragma unroll
        for (int T = 0; T < 4; ++T) {
            const int bb = HALO + 16 * (64 * half + 16 * T + lane16) + 8 * hlo;
            #pragma unroll
            for (int c = 0; c < 3; ++c)
                Bv[T][c] = *reinterpret_cast<const short8v*>(&xr[bb - 16 * (2 * c + hhi)]);
        }

        // Toeplitz band: lane l writes K[l] into 16 rows (same cols every route)
        #pragma unroll
        for (int r = 0; r < 16; ++r)
            mytab[TABS * r + 80 + r - l] = kvCur;

        // A-fragments (same-wave DS: ordered after the writes above)
        const int abase = TABS * lane16 + 80 + 8 * hlo;
        short8v A0 = *reinterpret_cast<const short8v*>(&mytab[abase - 16 * (0 + hhi)]);
        short8v A1 = *reinterpret_cast<const short8v*>(&mytab[abase - 16 * (2 + hhi)]);
        short8v A2 = *reinterpret_cast<const short8v*>(&mytab[abase - 16 * (4 + hhi)]);

        // prefetch next route's src + K value + metadata
        int srcNext = srcCur;
        unsigned short kvNext = kvCur;
        if (i + 1 < nr) {
            srcNext = sN;
            kvNext  = Kb[(size_t)eN * TK + l];
            if (i + 2 < nr) {
                int2 m = elist2[tgt * CAP + i + 1];
                eN = __builtin_amdgcn_readfirstlane(m.x);
                sN = __builtin_amdgcn_readfirstlane(m.y);
            }
        }

        #pragma unroll
        for (int T = 0; T < 4; ++T) {
            acc[T] = __builtin_amdgcn_mfma_f32_16x16x32_bf16(A0, Bv[T][0], acc[T], 0, 0, 0);
            acc[T] = __builtin_amdgcn_mfma_f32_16x16x32_bf16(A1, Bv[T][1], acc[T], 0, 0, 0);
            acc[T] = __builtin_amdgcn_mfma_f32_16x16x32_bf16(A2, Bv[T][2], acc[T], 0, 0, 0);
        }

        srcCur = srcNext;
        kvCur  = kvNext;
    }

    float* yrow = y + ((size_t)b * NN + tgt) * TT;
    #pragma unroll
    for (int T = 0; T < 4; ++T) {
        int tb = 16 * (64 * half + 16 * T + lane16) + 4 * h;
        float4v v = acc[T];
        __builtin_nontemporal_store(v, reinterpret_cast<float4v*>(yrow + tb));
    }
}

// ---------------------------------------------------------------------------
extern "C" void kernel_launch(void* const* d_in, const int* in_sizes, int n_in,
                              void* d_out, int out_size, void* d_ws, size_t ws_size,
                              hipStream_t stream) {
    const float* x      = (const float*)d_in[0];
    const float* params = (const float*)d_in[1];
    const int*   esrc   = (const int*)d_in[2];
    const int*   etgt   = (const int*)d_in[3];
    float* y = (float*)d_out;

    char* w = (char*)d_ws;
    float*          hirf   = (float*)w;          w += (size_t)NN * TK * 4;       // 1 MB
    unsigned short* hb     = (unsigned short*)w; w += (size_t)NN * TK * 2;       // 0.5 MB
    unsigned short* Kb     = (unsigned short*)w; w += (size_t)EE * TK * 2;       // 1 MB
    int*            cnt    = (int*)w;            w += (size_t)NN * 4;            // 16 KB
    int2*           elist2 = (int2*)w;           w += (size_t)NN * CAP * 8;      // 1 MB
    unsigned short* xb     = (unsigned short*)w; w += (size_t)2 * NN * XROW * 2; // 34.9 MB
    (void)ws_size;  // harness provides ~256 MB (observed via its poison fill)

    hipLaunchKernelGGL(prep_kernel, dim3(2064), dim3(256), 0, stream,
                       params, x, hirf, hb, xb, cnt);
    hipLaunchKernelGGL(kedge_kernel, dim3(EE / 4), dim3(256), 0, stream,
                       hirf, esrc, etgt, Kb, cnt, elist2);
    hipLaunchKernelGGL(conv_dg_kernel, dim3(NN), dim3(256), 0, stream,
                       xb, hb, Kb, elist2, cnt, y);
}